// Round 1
// baseline (16788.193 us; speedup 1.0000x reference)
//
#include <hip/hip_runtime.h>
#include <hip/hip_bf16.h>
#include <math.h>

#define C   768
#define HN  8
#define HS  96
#define NE  8
#define NL  12
#define NV  95
#define TT  64
#define NB  16
#define NTOK 1024   // NB*TT
#define H4  3072    // 4*C
#define NKR 2048    // NTOK * top_k

typedef __attribute__((ext_vector_type(8))) short short8;
typedef __attribute__((ext_vector_type(4))) float floatx4;

__device__ __forceinline__ short bf16_rne(float f) {
  union { float f; unsigned u; } x; x.f = f;
  unsigned r = x.u + 0x7FFFu + ((x.u >> 16) & 1u);
  return (short)(r >> 16);
}
__device__ __forceinline__ float bf16_to_f(short s) {
  union { unsigned u; float f; } x; x.u = ((unsigned)(unsigned short)s) << 16;
  return x.f;
}

// ---------------- split-bf16 MFMA GEMM (fp32 in/out, ~fp32 accuracy) --------
// Wave computes 32x32 (2x2 of 16x16x32 tiles); block = 4 waves = 64x64 tile.
// A [*,K] row-major, W [K,N] row-major. Per tile: 3 MFMAs (hi*lo, lo*hi, hi*hi).
__device__ __forceinline__ void gemm_block_body(
    const float* __restrict__ A, const float* __restrict__ W,
    const float* __restrict__ bias, float* __restrict__ Out,
    int row0, int Mend, int col0, int N, int K, int act)
{
  const int tid  = threadIdx.x;
  const int lane = tid & 63;
  const int wv   = tid >> 6;
  const int wr   = wv >> 1, wc = wv & 1;
  const int l16  = lane & 15, lq = lane >> 4;

  const int rA0 = row0 + wr * 32 + l16;
  const int rA1 = rA0 + 16;
  const int cB0 = col0 + wc * 32 + l16;
  const int cB1 = cB0 + 16;
  const bool va0 = rA0 < Mend, va1 = rA1 < Mend;
  const bool vb0 = cB0 < N,    vb1 = cB1 < N;

  floatx4 acc00 = {0,0,0,0}, acc01 = {0,0,0,0}, acc10 = {0,0,0,0}, acc11 = {0,0,0,0};

  for (int k0 = 0; k0 < K; k0 += 32) {
    const int kk = k0 + lq * 8;
    short8 a0h, a0l, a1h, a1l, b0h, b0l, b1h, b1l;
    {
      const float* p = A + (size_t)rA0 * K + kk;
      #pragma unroll
      for (int i = 0; i < 8; ++i) {
        float f = va0 ? p[i] : 0.f;
        short h = bf16_rne(f); a0h[i] = h; a0l[i] = bf16_rne(f - bf16_to_f(h));
      }
    }
    {
      const float* p = A + (size_t)rA1 * K + kk;
      #pragma unroll
      for (int i = 0; i < 8; ++i) {
        float f = va1 ? p[i] : 0.f;
        short h = bf16_rne(f); a1h[i] = h; a1l[i] = bf16_rne(f - bf16_to_f(h));
      }
    }
    {
      #pragma unroll
      for (int i = 0; i < 8; ++i) {
        float f = vb0 ? W[(size_t)(kk + i) * N + cB0] : 0.f;
        short h = bf16_rne(f); b0h[i] = h; b0l[i] = bf16_rne(f - bf16_to_f(h));
      }
    }
    {
      #pragma unroll
      for (int i = 0; i < 8; ++i) {
        float f = vb1 ? W[(size_t)(kk + i) * N + cB1] : 0.f;
        short h = bf16_rne(f); b1h[i] = h; b1l[i] = bf16_rne(f - bf16_to_f(h));
      }
    }
    acc00 = __builtin_amdgcn_mfma_f32_16x16x32_bf16(a0h, b0l, acc00, 0, 0, 0);
    acc00 = __builtin_amdgcn_mfma_f32_16x16x32_bf16(a0l, b0h, acc00, 0, 0, 0);
    acc00 = __builtin_amdgcn_mfma_f32_16x16x32_bf16(a0h, b0h, acc00, 0, 0, 0);
    acc01 = __builtin_amdgcn_mfma_f32_16x16x32_bf16(a0h, b1l, acc01, 0, 0, 0);
    acc01 = __builtin_amdgcn_mfma_f32_16x16x32_bf16(a0l, b1h, acc01, 0, 0, 0);
    acc01 = __builtin_amdgcn_mfma_f32_16x16x32_bf16(a0h, b1h, acc01, 0, 0, 0);
    acc10 = __builtin_amdgcn_mfma_f32_16x16x32_bf16(a1h, b0l, acc10, 0, 0, 0);
    acc10 = __builtin_amdgcn_mfma_f32_16x16x32_bf16(a1l, b0h, acc10, 0, 0, 0);
    acc10 = __builtin_amdgcn_mfma_f32_16x16x32_bf16(a1h, b0h, acc10, 0, 0, 0);
    acc11 = __builtin_amdgcn_mfma_f32_16x16x32_bf16(a1h, b1l, acc11, 0, 0, 0);
    acc11 = __builtin_amdgcn_mfma_f32_16x16x32_bf16(a1l, b1h, acc11, 0, 0, 0);
    acc11 = __builtin_amdgcn_mfma_f32_16x16x32_bf16(a1h, b1h, acc11, 0, 0, 0);
  }

  const int rb0 = row0 + wr * 32 + lq * 4;
  auto store4 = [&](floatx4 acc, int rbase, int col, bool vcol) {
    if (!vcol) return;
    float bb = bias ? bias[col] : 0.f;
    #pragma unroll
    for (int r = 0; r < 4; ++r) {
      int row = rbase + r;
      if (row < Mend) {
        float v = acc[r] + bb;
        if (act == 1) v = 0.5f * v * (1.f + erff(v * 0.70710678118654752f));
        Out[(size_t)row * N + col] = v;
      }
    }
  };
  store4(acc00, rb0,      cB0, vb0);
  store4(acc01, rb0,      cB1, vb1);
  store4(acc10, rb0 + 16, cB0, vb0);
  store4(acc11, rb0 + 16, cB1, vb1);
}

__global__ void __launch_bounds__(256) k_gemm(const float* A, const float* W, const float* bias,
    float* Out, int M, int N, int K, int act) {
  gemm_block_body(A, W, bias, Out, blockIdx.y * 64, M, blockIdx.x * 64, N, K, act);
}

__global__ void __launch_bounds__(256) k_qkv(const float* A, const float* W0, const float* W1p,
    const float* W2p, float* o0, float* o1, float* o2, int M, int N, int K) {
  const float* Ws = blockIdx.z == 0 ? W0 : (blockIdx.z == 1 ? W1p : W2p);
  float*       Os = blockIdx.z == 0 ? o0 : (blockIdx.z == 1 ? o1 : o2);
  gemm_block_body(A, Ws, nullptr, Os, blockIdx.y * 64, M, blockIdx.x * 64, N, K, 0);
}

// grouped (per-expert) GEMM over gathered rows; grid.z = expert
__global__ void __launch_bounds__(256) k_gemm_grp(const float* A, const float* Wbase, const float* bbase,
    float* Out, const int* __restrict__ counts, const int* __restrict__ offs,
    int N, int K, long strideW, int strideB, int act) {
  int e = blockIdx.z;
  int cnt = counts[e];
  int r0 = blockIdx.y * 64;
  if (r0 >= cnt) return;
  int off = offs[e];
  gemm_block_body(A, Wbase + (size_t)e * strideW, bbase + (size_t)e * strideB, Out,
                  off + r0, off + cnt, blockIdx.x * 64, N, K, act);
}

// ---------------- small ops ------------------------------------------------
__global__ void k_embed(const int* __restrict__ idx, const float* __restrict__ tok,
                        const float* __restrict__ pos, float* __restrict__ x) {
  int n = blockIdx.x; int t = n & (TT - 1);
  int token = idx[n];
  for (int j = threadIdx.x; j < C; j += 256)
    x[(size_t)n * C + j] = tok[(size_t)token * C + j] + pos[(size_t)t * C + j];
}

__global__ void __launch_bounds__(256) k_ln(const float* __restrict__ xin, const float* __restrict__ yin,
    const float* __restrict__ g, const float* __restrict__ b, float* __restrict__ out) {
  int n = blockIdx.x; int tid = threadIdx.x;
  int lane = tid & 63, wid = tid >> 6;
  __shared__ float sp[4];
  float v[3];
  #pragma unroll
  for (int i = 0; i < 3; ++i) {
    int c = tid + i * 256;
    float t = xin[(size_t)n * C + c];
    if (yin) t += yin[(size_t)n * C + c];
    v[i] = t;
  }
  float s = v[0] + v[1] + v[2];
  for (int o = 32; o; o >>= 1) s += __shfl_down(s, o);
  if (!lane) sp[wid] = s;
  __syncthreads();
  float mean = (sp[0] + sp[1] + sp[2] + sp[3]) * (1.f / C);
  __syncthreads();
  float d0 = v[0] - mean, d1 = v[1] - mean, d2 = v[2] - mean;
  float qq = d0 * d0 + d1 * d1 + d2 * d2;
  for (int o = 32; o; o >>= 1) qq += __shfl_down(qq, o);
  if (!lane) sp[wid] = qq;
  __syncthreads();
  float var = (sp[0] + sp[1] + sp[2] + sp[3]) * (1.f / C);
  float rs = rsqrtf(var + 1e-5f);
  #pragma unroll
  for (int i = 0; i < 3; ++i) {
    int c = tid + i * 256;
    out[(size_t)n * C + c] = (v[i] - mean) * rs * g[c] + b[c];
  }
}

__global__ void __launch_bounds__(256) k_attn(const float* __restrict__ q, const float* __restrict__ kp,
    const float* __restrict__ vp, float* __restrict__ o) {
  int bh = blockIdx.x; int b = bh >> 3, h = bh & 7;
  __shared__ float kv[TT][HS];
  __shared__ float sc[TT][TT + 1];
  int tid = threadIdx.x;
  for (int i = tid; i < TT * HS; i += 256) {
    int t = i / HS, d = i % HS;
    kv[t][d] = kp[(size_t)(b * TT + t) * C + h * HS + d];
  }
  __syncthreads();
  int r = tid >> 2, g = tid & 3;
  const float scale = 0.10206207261596575f; // 96^-0.5
  const float* qrow = q + (size_t)(b * TT + r) * C + h * HS;
  const floatx4* q4 = (const floatx4*)qrow;
  for (int kk = g * 16; kk < g * 16 + 16; ++kk) {
    float s = 0.f;
    if (kk <= r) {
      const floatx4* k4 = (const floatx4*)&kv[kk][0];
      float acc = 0.f;
      #pragma unroll
      for (int d4 = 0; d4 < HS / 4; ++d4) {
        floatx4 a = q4[d4], bb = k4[d4];
        acc += a[0] * bb[0] + a[1] * bb[1] + a[2] * bb[2] + a[3] * bb[3];
      }
      s = acc * scale;
    }
    sc[r][kk] = s;
  }
  __syncthreads();
  if (g == 0) {
    float m = -1e30f;
    for (int kk = 0; kk <= r; ++kk) m = fmaxf(m, sc[r][kk]);
    float den = 0.f;
    for (int kk = 0; kk <= r; ++kk) { float e2 = expf(sc[r][kk] - m); den += e2; sc[r][kk] = e2; }
    float inv = 1.f / den;
    for (int kk = 0; kk <= r; ++kk) sc[r][kk] *= inv;
    for (int kk = r + 1; kk < TT; ++kk) sc[r][kk] = 0.f;
  }
  __syncthreads();
  for (int i = tid; i < TT * HS; i += 256) {
    int t = i / HS, d = i % HS;
    kv[t][d] = vp[(size_t)(b * TT + t) * C + h * HS + d];
  }
  __syncthreads();
  floatx4 accv[6];
  #pragma unroll
  for (int cc = 0; cc < 6; ++cc) accv[cc] = (floatx4){0,0,0,0};
  for (int kk = 0; kk < TT; ++kk) {
    float wgt = sc[r][kk];
    const floatx4* v4 = (const floatx4*)&kv[kk][0];
    #pragma unroll
    for (int cc = 0; cc < 6; ++cc) accv[cc] += wgt * v4[g * 6 + cc];
  }
  float* orow = o + (size_t)(b * TT + r) * C + h * HS + g * 24;
  #pragma unroll
  for (int cc = 0; cc < 6; ++cc) ((floatx4*)orow)[cc] = accv[cc];
}

__global__ void __launch_bounds__(64) k_gate(const float* __restrict__ x, const float* __restrict__ gW,
    const float* __restrict__ gb, int* __restrict__ ti, float* __restrict__ tp,
    int* __restrict__ pos, int* __restrict__ counts) {
  int n = blockIdx.x; int lane = threadIdx.x;
  float a[NE];
  #pragma unroll
  for (int e = 0; e < NE; ++e) a[e] = 0.f;
  for (int c = lane; c < C; c += 64) {
    float xv = x[(size_t)n * C + c];
    const float* wr_ = gW + (size_t)c * NE;
    #pragma unroll
    for (int e = 0; e < NE; ++e) a[e] += xv * wr_[e];
  }
  #pragma unroll
  for (int e = 0; e < NE; ++e)
    for (int o = 32; o; o >>= 1) a[e] += __shfl_down(a[e], o);
  if (lane == 0) {
    float p[NE]; float m = -1e30f;
    #pragma unroll
    for (int e = 0; e < NE; ++e) { a[e] += gb[e]; m = fmaxf(m, a[e]); }
    float den = 0.f;
    #pragma unroll
    for (int e = 0; e < NE; ++e) { p[e] = expf(a[e] - m); den += p[e]; }
    float inv = 1.f / den;
    #pragma unroll
    for (int e = 0; e < NE; ++e) p[e] *= inv;
    int e0 = 0;
    for (int e = 1; e < NE; ++e) if (p[e] > p[e0]) e0 = e;
    int e1 = -1;
    for (int e = 0; e < NE; ++e) if (e != e0 && (e1 < 0 || p[e] > p[e1])) e1 = e;
    float ssum = p[e0] + p[e1];
    int p0 = atomicAdd(&counts[e0], 1), p1 = atomicAdd(&counts[e1], 1);
    ti[n * 2] = e0;  ti[n * 2 + 1] = e1;
    pos[n * 2] = p0; pos[n * 2 + 1] = p1;
    tp[n * 2] = p[e0] / ssum; tp[n * 2 + 1] = p[e1] / ssum;
  }
}

__global__ void k_offs(const int* __restrict__ counts, int* __restrict__ offs) {
  if (threadIdx.x == 0) {
    int run = 0;
    for (int e = 0; e < NE; ++e) { offs[e] = run; run += counts[e]; }
  }
}

__global__ void __launch_bounds__(256) k_gather(const float* __restrict__ x, const int* __restrict__ ti,
    const int* __restrict__ pos, const int* __restrict__ offs,
    int* __restrict__ rowOf, float* __restrict__ Xg) {
  int a = blockIdx.x; int n = a >> 1;
  int row = offs[ti[a]] + pos[a];
  if (threadIdx.x == 0) rowOf[a] = row;
  const floatx4* src = (const floatx4*)(x + (size_t)n * C);
  floatx4* dst = (floatx4*)(Xg + (size_t)row * C);
  for (int i = threadIdx.x; i < C / 4; i += 256) dst[i] = src[i];
}

__global__ void __launch_bounds__(256) k_comb(const float* __restrict__ Yg, const int* __restrict__ rowOf,
    const float* __restrict__ tp, float* __restrict__ y) {
  int n = blockIdx.x;
  int r0 = rowOf[n * 2], r1 = rowOf[n * 2 + 1];
  float w0 = tp[n * 2], w1 = tp[n * 2 + 1];
  const floatx4* s0 = (const floatx4*)(Yg + (size_t)r0 * C);
  const floatx4* s1 = (const floatx4*)(Yg + (size_t)r1 * C);
  floatx4* dst = (floatx4*)(y + (size_t)n * C);
  for (int i = threadIdx.x; i < C / 4; i += 256) dst[i] = w0 * s0[i] + w1 * s1[i];
}

// ---------------- driver ---------------------------------------------------
extern "C" void kernel_launch(void* const* d_in, const int* in_sizes, int n_in,
                              void* d_out, int out_size, void* d_ws, size_t ws_size,
                              hipStream_t stream) {
  const int*   idx   = (const int*)d_in[0];
  const float* tok   = (const float*)d_in[1];
  const float* pose  = (const float*)d_in[2];
  const float* Wq    = (const float*)d_in[3];
  const float* Wk    = (const float*)d_in[4];
  const float* Wv    = (const float*)d_in[5];
  const float* Wo    = (const float*)d_in[6];
  const float* bo    = (const float*)d_in[7];
  const float* gW    = (const float*)d_in[8];
  const float* gb    = (const float*)d_in[9];
  const float* W1    = (const float*)d_in[10];
  const float* b1    = (const float*)d_in[11];
  const float* W2    = (const float*)d_in[12];
  const float* b2    = (const float*)d_in[13];
  const float* ln1g  = (const float*)d_in[14];
  const float* ln1b  = (const float*)d_in[15];
  const float* ln2g  = (const float*)d_in[16];
  const float* ln2b  = (const float*)d_in[17];
  const float* lnfg  = (const float*)d_in[18];
  const float* lnfb  = (const float*)d_in[19];
  const float* headW = (const float*)d_in[20];
  const float* headb = (const float*)d_in[21];
  float* out = (float*)d_out;

  // workspace layout (~57 MB)
  if (ws_size < (size_t)60 * 1024 * 1024) return;
  char* w = (char*)d_ws;
  auto alloc = [&](size_t nf) { float* p = (float*)w; w += nf * sizeof(float); return p; };
  float* x  = alloc((size_t)NTOK * C);
  float* y  = alloc((size_t)NTOK * C);
  float* q  = alloc((size_t)NTOK * C);
  float* kb = alloc((size_t)NTOK * C);
  float* vb = alloc((size_t)NTOK * C);
  float* ob = alloc((size_t)NTOK * C);
  float* Xg = alloc((size_t)NKR * C);
  float* Yg = alloc((size_t)NKR * C);
  float* Hg = alloc((size_t)NKR * H4);
  float* tp = alloc(NKR);
  int* ti     = (int*)w; w += NKR * sizeof(int);
  int* posA   = (int*)w; w += NKR * sizeof(int);
  int* rowOf  = (int*)w; w += NKR * sizeof(int);
  int* counts = (int*)w; w += NE * sizeof(int);
  int* offs   = (int*)w; w += NE * sizeof(int);

  k_embed<<<NTOK, 256, 0, stream>>>(idx, tok, pose, x);

  for (int l = 0; l < NL; ++l) {
    const float* wq = Wq + (size_t)l * C * C;
    const float* wk = Wk + (size_t)l * C * C;
    const float* wv = Wv + (size_t)l * C * C;
    const float* wo = Wo + (size_t)l * C * C;

    k_qkv<<<dim3(C / 64, NTOK / 64, 3), 256, 0, stream>>>(x, wq, wk, wv, q, kb, vb, NTOK, C, C);
    k_attn<<<NB * HN, 256, 0, stream>>>(q, kb, vb, ob);
    k_gemm<<<dim3(C / 64, NTOK / 64), 256, 0, stream>>>(ob, wo, bo + (size_t)l * C, y, NTOK, C, C, 0);
    k_ln<<<NTOK, 256, 0, stream>>>(x, y, ln1g + (size_t)l * C, ln1b + (size_t)l * C, x);

    hipMemsetAsync(counts, 0, NE * sizeof(int), stream);
    k_gate<<<NTOK, 64, 0, stream>>>(x, gW + (size_t)l * C * NE, gb + (size_t)l * NE, ti, tp, posA, counts);
    k_offs<<<1, 64, 0, stream>>>(counts, offs);
    k_gather<<<NKR, 256, 0, stream>>>(x, ti, posA, offs, rowOf, Xg);
    k_gemm_grp<<<dim3(H4 / 64, NKR / 64, NE), 256, 0, stream>>>(Xg, W1 + (size_t)l * NE * C * H4,
        b1 + (size_t)l * NE * H4, Hg, counts, offs, H4, C, (long)C * H4, H4, 1);
    k_gemm_grp<<<dim3(C / 64, NKR / 64, NE), 256, 0, stream>>>(Hg, W2 + (size_t)l * NE * H4 * C,
        b2 + (size_t)l * NE * C, Yg, counts, offs, C, H4, (long)H4 * C, C, 0);
    k_comb<<<NTOK, 256, 0, stream>>>(Yg, rowOf, tp, y);
    k_ln<<<NTOK, 256, 0, stream>>>(x, y, ln2g + (size_t)l * C, ln2b + (size_t)l * C, x);
  }

  k_ln<<<NTOK, 256, 0, stream>>>(x, nullptr, lnfg, lnfb, x);
  k_gemm<<<dim3((NV + 63) / 64, NTOK / 64), 256, 0, stream>>>(x, headW, headb, out, NTOK, NV, C, 0);
}

// Round 2
// 12438.712 us; speedup vs baseline: 1.3497x; 1.3497x over previous
//
#include <hip/hip_runtime.h>
#include <math.h>

#define C    768
#define HN   8
#define HS   96
#define NE   8
#define NL   12
#define NV   95
#define TT   64
#define NB   16
#define NTOK 1024
#define H4   3072
#define NKR  2048
#define NKRP 2176   // padded gathered-row count (blocks may read 128 past cnt)

typedef __attribute__((ext_vector_type(8))) short short8;
typedef __attribute__((ext_vector_type(4))) float floatx4;

union U16x8 { uint4 u; short8 s; };
__device__ __forceinline__ short8 as_s8(uint4 u) { U16x8 x; x.u = u; return x.s; }
__device__ __forceinline__ uint4 ror16x4(uint4 q) {
  uint4 r;
  r.x = (q.x >> 16) | (q.x << 16);
  r.y = (q.y >> 16) | (q.y << 16);
  r.z = (q.z >> 16) | (q.z << 16);
  r.w = (q.w >> 16) | (q.w << 16);
  return r;
}

// packed split: low16 = bf16(hi), high16 = bf16(residual); hi+lo == f to ~2^-17 rel
__device__ __forceinline__ unsigned pack_split(float f) {
  unsigned u = __float_as_uint(f);
  unsigned h = (u + 0x7fffu + ((u >> 16) & 1u)) >> 16;
  float d = f - __uint_as_float(h << 16);
  unsigned v = __float_as_uint(d);
  unsigned l = (v + 0x7fffu + ((v >> 16) & 1u)) >> 16;
  return h | (l << 16);
}
__device__ __forceinline__ float unpack_split(unsigned w) {
  return __uint_as_float(w << 16) + __uint_as_float(w & 0xffff0000u);
}

// ---------------- double-bf16 MFMA GEMM -------------------------------------
// A: packed-split u32 [*,K]; W: fp32 [K,N] staged->LDS as packed-split,
// transposed + XOR-swizzled. Two MFMA passes ([h,l] and [l,h]-rotated B) give
// exactly (Ah+Al)(Bh+Bl). Block = 256 thr = 4 waves; tile 128x128; BK=32.
template<int ACT, int OUTF>   // ACT: 1=gelu; OUTF: 0=fp32 out, 1=packed out
__device__ __forceinline__ void gemm_body(
    const unsigned* __restrict__ Ap, const float* __restrict__ W,
    const float* __restrict__ bias, float* __restrict__ outF,
    unsigned* __restrict__ outP,
    int row0, int Mend, int col0, int N, int K)
{
  __shared__ unsigned Bt[2][128 * 32];
  const int tid  = threadIdx.x;
  const int lane = tid & 63, wv = tid >> 6;
  const int l16  = lane & 15, lq = lane >> 4;
  const int sw   = (l16 & 7) << 2;          // read-side XOR swizzle
  const int kS   = tid & 31, cg = tid >> 5; // staging: k-row, col-group
  const int colS = col0 + cg * 16;
  const bool vok = (col0 + 128) <= N;
  const int ns   = K >> 5;

  const unsigned* A0 = Ap + (size_t)(row0 + wv * 32 + l16) * K;
  const unsigned* A1 = A0 + (size_t)16 * K;

  floatx4 acc[2][8];
  #pragma unroll
  for (int h = 0; h < 2; ++h)
    #pragma unroll
    for (int f = 0; f < 8; ++f) acc[h][f] = (floatx4){0, 0, 0, 0};

  float bw[16];
  auto loadB = [&](int s) {
    const float* src = W + (size_t)(s * 32 + kS) * N;
    if (vok) {
      #pragma unroll
      for (int j = 0; j < 4; ++j) {
        float4 t = *(const float4*)(src + colS + j * 4);
        bw[j*4+0] = t.x; bw[j*4+1] = t.y; bw[j*4+2] = t.z; bw[j*4+3] = t.w;
      }
    } else {
      #pragma unroll
      for (int j = 0; j < 16; ++j) {
        int c = colS + j; c = c < N ? c : N - 1;   // clamp (junk cols masked at store)
        bw[j] = src[c];
      }
    }
  };
  auto writeB = [&](int b) {
    #pragma unroll
    for (int j = 0; j < 16; ++j) {
      int col = cg * 16 + j;
      Bt[b][col * 32 + (kS ^ ((col & 7) << 2))] = pack_split(bw[j]);
    }
  };

  uint4 ac0[2], ac1[2];
  auto loadA = [&](int s, uint4* d0, uint4* d1) {
    const unsigned* p = A0 + s * 32;
    d0[0] = *(const uint4*)(p + lq * 4);
    d0[1] = *(const uint4*)(p + 16 + lq * 4);
    p = A1 + s * 32;
    d1[0] = *(const uint4*)(p + lq * 4);
    d1[1] = *(const uint4*)(p + 16 + lq * 4);
  };

  loadB(0);
  loadA(0, ac0, ac1);
  writeB(0);

  for (int s = 0; s < ns; ++s) {
    const int b = s & 1;
    __syncthreads();
    const int sn = (s + 1 < ns) ? s + 1 : s;
    loadB(sn);                       // issue global loads early
    uint4 na0[2], na1[2];
    loadA(sn, na0, na1);
    // compute current tile
    const unsigned* bp = Bt[b];
    #pragma unroll
    for (int f = 0; f < 8; ++f) {
      const unsigned* base = bp + (f * 16 + l16) * 32;
      uint4 q0 = *(const uint4*)(base + ((4 * lq) ^ sw));
      uint4 q1 = *(const uint4*)(base + ((16 + 4 * lq) ^ sw));
      short8 b0 = as_s8(q0), b0r = as_s8(ror16x4(q0));
      short8 b1 = as_s8(q1), b1r = as_s8(ror16x4(q1));
      short8 a00 = as_s8(ac0[0]), a01 = as_s8(ac0[1]);
      short8 a10 = as_s8(ac1[0]), a11 = as_s8(ac1[1]);
      acc[0][f] = __builtin_amdgcn_mfma_f32_16x16x32_bf16(a00, b0,  acc[0][f], 0, 0, 0);
      acc[1][f] = __builtin_amdgcn_mfma_f32_16x16x32_bf16(a10, b0,  acc[1][f], 0, 0, 0);
      acc[0][f] = __builtin_amdgcn_mfma_f32_16x16x32_bf16(a00, b0r, acc[0][f], 0, 0, 0);
      acc[1][f] = __builtin_amdgcn_mfma_f32_16x16x32_bf16(a10, b0r, acc[1][f], 0, 0, 0);
      acc[0][f] = __builtin_amdgcn_mfma_f32_16x16x32_bf16(a01, b1,  acc[0][f], 0, 0, 0);
      acc[1][f] = __builtin_amdgcn_mfma_f32_16x16x32_bf16(a11, b1,  acc[1][f], 0, 0, 0);
      acc[0][f] = __builtin_amdgcn_mfma_f32_16x16x32_bf16(a01, b1r, acc[0][f], 0, 0, 0);
      acc[1][f] = __builtin_amdgcn_mfma_f32_16x16x32_bf16(a11, b1r, acc[1][f], 0, 0, 0);
    }
    if (s + 1 < ns) writeB(b ^ 1);   // cvt + ds_write after compute (T14)
    ac0[0] = na0[0]; ac0[1] = na0[1]; ac1[0] = na1[0]; ac1[1] = na1[1];
  }

  const int rb = row0 + wv * 32 + lq * 4;
  #pragma unroll
  for (int h = 0; h < 2; ++h) {
    #pragma unroll
    for (int f = 0; f < 8; ++f) {
      int cc = col0 + f * 16 + l16;
      if (cc < N) {
        float bb = bias ? bias[cc] : 0.f;
        #pragma unroll
        for (int m = 0; m < 4; ++m) {
          int rr = rb + h * 16 + m;
          if (rr < Mend) {
            float v = acc[h][f][m] + bb;
            if (ACT) v = 0.5f * v * (1.f + erff(v * 0.70710678118654752f));
            if (OUTF == 0) outF[(size_t)rr * N + cc] = v;
            else           outP[(size_t)rr * N + cc] = pack_split(v);
          }
        }
      }
    }
  }
}

__global__ void __launch_bounds__(256) k_qkv(const unsigned* Ap, const float* W0,
    const float* W1p, const float* W2p, float* o0, float* o1, float* o2) {
  const float* Ws = blockIdx.z == 0 ? W0 : (blockIdx.z == 1 ? W1p : W2p);
  float*       Os = blockIdx.z == 0 ? o0 : (blockIdx.z == 1 ? o1 : o2);
  gemm_body<0, 0>(Ap, Ws, nullptr, Os, nullptr, blockIdx.y * 128, NTOK,
                  blockIdx.x * 128, C, C);
}

__global__ void __launch_bounds__(256) k_wo(const unsigned* Ap, const float* W,
    const float* bias, float* Out) {
  gemm_body<0, 0>(Ap, W, bias, Out, nullptr, blockIdx.y * 128, NTOK,
                  blockIdx.x * 128, C, C);
}

__global__ void __launch_bounds__(256) k_w1(const unsigned* Ap, const float* Wb,
    const float* bb, unsigned* Out, const int* __restrict__ counts,
    const int* __restrict__ offs) {
  int e = blockIdx.z, cnt = counts[e], r0 = blockIdx.y * 128;
  if (r0 >= cnt) return;
  int off = offs[e];
  gemm_body<1, 1>(Ap, Wb + (size_t)e * C * H4, bb + (size_t)e * H4, nullptr, Out,
                  off + r0, off + cnt, blockIdx.x * 128, H4, C);
}

__global__ void __launch_bounds__(256) k_w2(const unsigned* Ap, const float* Wb,
    const float* bb, float* Out, const int* __restrict__ counts,
    const int* __restrict__ offs) {
  int e = blockIdx.z, cnt = counts[e], r0 = blockIdx.y * 128;
  if (r0 >= cnt) return;
  int off = offs[e];
  gemm_body<0, 0>(Ap, Wb + (size_t)e * H4 * C, bb + (size_t)e * C, Out, nullptr,
                  off + r0, off + cnt, blockIdx.x * 128, C, H4);
}

__global__ void __launch_bounds__(256) k_head(const unsigned* Ap, const float* W,
    const float* bias, float* Out) {
  gemm_body<0, 0>(Ap, W, bias, Out, nullptr, blockIdx.y * 128, NTOK, 0, NV, C);
}

// ---------------- small ops ------------------------------------------------
__global__ void k_embed(const int* __restrict__ idx, const float* __restrict__ tok,
                        const float* __restrict__ pos, unsigned* __restrict__ xp) {
  int n = blockIdx.x; int t = n & (TT - 1);
  int token = idx[n];
  for (int j = threadIdx.x; j < C; j += 256)
    xp[(size_t)n * C + j] = pack_split(tok[(size_t)token * C + j] + pos[(size_t)t * C + j]);
}

__device__ __forceinline__ void ln_core(int tid, float* v, const float* g,
                                        const float* bb, unsigned* outrow) {
  int lane = tid & 63, wid = tid >> 6;
  __shared__ float sp[4];
  float s = v[0] + v[1] + v[2];
  for (int o = 32; o; o >>= 1) s += __shfl_down(s, o);
  if (!lane) sp[wid] = s;
  __syncthreads();
  float mean = (sp[0] + sp[1] + sp[2] + sp[3]) * (1.f / C);
  __syncthreads();
  float d0 = v[0] - mean, d1 = v[1] - mean, d2 = v[2] - mean;
  float qq = d0 * d0 + d1 * d1 + d2 * d2;
  for (int o = 32; o; o >>= 1) qq += __shfl_down(qq, o);
  if (!lane) sp[wid] = qq;
  __syncthreads();
  float var = (sp[0] + sp[1] + sp[2] + sp[3]) * (1.f / C);
  float rs = rsqrtf(var + 1e-5f);
  #pragma unroll
  for (int i = 0; i < 3; ++i) {
    int c = tid + i * 256;
    outrow[c] = pack_split((v[i] - mean) * rs * g[c] + bb[c]);
  }
}

__global__ void __launch_bounds__(256) k_ln(const unsigned* __restrict__ xp,
    const float* __restrict__ y, const float* __restrict__ g,
    const float* __restrict__ bb, unsigned* __restrict__ outp) {
  int n = blockIdx.x; int tid = threadIdx.x;
  float v[3];
  #pragma unroll
  for (int i = 0; i < 3; ++i) {
    int c = tid + i * 256;
    float t = unpack_split(xp[(size_t)n * C + c]);
    if (y) t += y[(size_t)n * C + c];
    v[i] = t;
  }
  ln_core(tid, v, g, bb, outp + (size_t)n * C);
}

__global__ void __launch_bounds__(256) k_ln_moe(const unsigned* __restrict__ xp,
    const float* __restrict__ Yg, const int* __restrict__ rowOf,
    const float* __restrict__ tp, const float* __restrict__ g,
    const float* __restrict__ bb, unsigned* __restrict__ outp) {
  int n = blockIdx.x; int tid = threadIdx.x;
  int r0 = rowOf[n * 2], r1 = rowOf[n * 2 + 1];
  float w0 = tp[n * 2], w1 = tp[n * 2 + 1];
  float v[3];
  #pragma unroll
  for (int i = 0; i < 3; ++i) {
    int c = tid + i * 256;
    v[i] = unpack_split(xp[(size_t)n * C + c])
         + w0 * Yg[(size_t)r0 * C + c] + w1 * Yg[(size_t)r1 * C + c];
  }
  ln_core(tid, v, g, bb, outp + (size_t)n * C);
}

__global__ void __launch_bounds__(256) k_attn(const float* __restrict__ q,
    const float* __restrict__ kp, const float* __restrict__ vp,
    unsigned* __restrict__ op) {
  int bh = blockIdx.x; int b = bh >> 3, h = bh & 7;
  __shared__ float kv[TT][HS];
  __shared__ float sc[TT][TT + 1];
  int tid = threadIdx.x;
  for (int i = tid; i < TT * HS; i += 256) {
    int t = i / HS, d = i % HS;
    kv[t][d] = kp[(size_t)(b * TT + t) * C + h * HS + d];
  }
  __syncthreads();
  int r = tid >> 2, g = tid & 3;
  const float scale = 0.10206207261596575f;
  const floatx4* q4 = (const floatx4*)(q + (size_t)(b * TT + r) * C + h * HS);
  for (int kk = g * 16; kk < g * 16 + 16; ++kk) {
    float s = 0.f;
    if (kk <= r) {
      const floatx4* k4 = (const floatx4*)&kv[kk][0];
      float a2 = 0.f;
      #pragma unroll
      for (int d4 = 0; d4 < HS / 4; ++d4) {
        floatx4 a = q4[d4], bbv = k4[d4];
        a2 += a[0]*bbv[0] + a[1]*bbv[1] + a[2]*bbv[2] + a[3]*bbv[3];
      }
      s = a2 * scale;
    }
    sc[r][kk] = s;
  }
  __syncthreads();
  if (g == 0) {
    float m = -1e30f;
    for (int kk = 0; kk <= r; ++kk) m = fmaxf(m, sc[r][kk]);
    float den = 0.f;
    for (int kk = 0; kk <= r; ++kk) { float e2 = expf(sc[r][kk] - m); den += e2; sc[r][kk] = e2; }
    float inv = 1.f / den;
    for (int kk = 0; kk <= r; ++kk) sc[r][kk] *= inv;
    for (int kk = r + 1; kk < TT; ++kk) sc[r][kk] = 0.f;
  }
  __syncthreads();
  for (int i = tid; i < TT * HS; i += 256) {
    int t = i / HS, d = i % HS;
    kv[t][d] = vp[(size_t)(b * TT + t) * C + h * HS + d];
  }
  __syncthreads();
  floatx4 accv[6];
  #pragma unroll
  for (int cc = 0; cc < 6; ++cc) accv[cc] = (floatx4){0, 0, 0, 0};
  for (int kk = 0; kk < TT; ++kk) {
    float wgt = sc[r][kk];
    const floatx4* v4 = (const floatx4*)&kv[kk][0];
    #pragma unroll
    for (int cc = 0; cc < 6; ++cc) accv[cc] += wgt * v4[g * 6 + cc];
  }
  unsigned* orow = op + (size_t)(b * TT + r) * C + h * HS + g * 24;
  #pragma unroll
  for (int cc = 0; cc < 6; ++cc)
    #pragma unroll
    for (int m = 0; m < 4; ++m) orow[cc * 4 + m] = pack_split(accv[cc][m]);
}

__global__ void __launch_bounds__(64) k_gate(const unsigned* __restrict__ xp,
    const float* __restrict__ gW, const float* __restrict__ gb,
    int* __restrict__ ti, float* __restrict__ tp, int* __restrict__ pos,
    int* __restrict__ counts) {
  int n = blockIdx.x; int lane = threadIdx.x;
  float a[NE];
  #pragma unroll
  for (int e = 0; e < NE; ++e) a[e] = 0.f;
  for (int c = lane; c < C; c += 64) {
    float xv = unpack_split(xp[(size_t)n * C + c]);
    const float* wr_ = gW + (size_t)c * NE;
    #pragma unroll
    for (int e = 0; e < NE; ++e) a[e] += xv * wr_[e];
  }
  #pragma unroll
  for (int e = 0; e < NE; ++e)
    for (int o = 32; o; o >>= 1) a[e] += __shfl_down(a[e], o);
  if (lane == 0) {
    float p[NE]; float m = -1e30f;
    #pragma unroll
    for (int e = 0; e < NE; ++e) { a[e] += gb[e]; m = fmaxf(m, a[e]); }
    float den = 0.f;
    #pragma unroll
    for (int e = 0; e < NE; ++e) { p[e] = expf(a[e] - m); den += p[e]; }
    float inv = 1.f / den;
    #pragma unroll
    for (int e = 0; e < NE; ++e) p[e] *= inv;
    int e0 = 0;
    for (int e = 1; e < NE; ++e) if (p[e] > p[e0]) e0 = e;
    int e1 = -1;
    for (int e = 0; e < NE; ++e) if (e != e0 && (e1 < 0 || p[e] > p[e1])) e1 = e;
    float ssum = p[e0] + p[e1];
    int p0 = atomicAdd(&counts[e0], 1), p1 = atomicAdd(&counts[e1], 1);
    ti[n * 2] = e0;  ti[n * 2 + 1] = e1;
    pos[n * 2] = p0; pos[n * 2 + 1] = p1;
    tp[n * 2] = p[e0] / ssum; tp[n * 2 + 1] = p[e1] / ssum;
  }
}

__global__ void k_offs(const int* __restrict__ counts, int* __restrict__ offs) {
  if (threadIdx.x == 0) {
    int run = 0;
    for (int e = 0; e < NE; ++e) { offs[e] = run; run += counts[e]; }
  }
}

__global__ void __launch_bounds__(64) k_gather(const unsigned* __restrict__ xp,
    const int* __restrict__ ti, const int* __restrict__ pos,
    const int* __restrict__ offs, int* __restrict__ rowOf,
    unsigned* __restrict__ Xgp) {
  int a = blockIdx.x; int n = a >> 1;
  int row = offs[ti[a]] + pos[a];
  if (threadIdx.x == 0) rowOf[a] = row;
  const uint4* s = (const uint4*)(xp + (size_t)n * C);
  uint4* d = (uint4*)(Xgp + (size_t)row * C);
  for (int i = threadIdx.x; i < C / 4; i += 64) d[i] = s[i];
}

// ---------------- driver ---------------------------------------------------
extern "C" void kernel_launch(void* const* d_in, const int* in_sizes, int n_in,
                              void* d_out, int out_size, void* d_ws, size_t ws_size,
                              hipStream_t stream) {
  const int*   idx   = (const int*)d_in[0];
  const float* tok   = (const float*)d_in[1];
  const float* pose  = (const float*)d_in[2];
  const float* Wq    = (const float*)d_in[3];
  const float* Wk    = (const float*)d_in[4];
  const float* Wv    = (const float*)d_in[5];
  const float* Wo    = (const float*)d_in[6];
  const float* bo    = (const float*)d_in[7];
  const float* gW    = (const float*)d_in[8];
  const float* gb    = (const float*)d_in[9];
  const float* W1    = (const float*)d_in[10];
  const float* b1    = (const float*)d_in[11];
  const float* W2    = (const float*)d_in[12];
  const float* b2    = (const float*)d_in[13];
  const float* ln1g  = (const float*)d_in[14];
  const float* ln1b  = (const float*)d_in[15];
  const float* ln2g  = (const float*)d_in[16];
  const float* ln2b  = (const float*)d_in[17];
  const float* lnfg  = (const float*)d_in[18];
  const float* lnfb  = (const float*)d_in[19];
  const float* headW = (const float*)d_in[20];
  const float* headb = (const float*)d_in[21];
  float* out = (float*)d_out;

  if (ws_size < (size_t)60 * 1024 * 1024) return;
  char* w = (char*)d_ws;
  auto allocU = [&](size_t n) { unsigned* p = (unsigned*)w; w += n * 4; return p; };
  auto allocF = [&](size_t n) { float* p = (float*)w; w += n * 4; return p; };
  unsigned* xp  = allocU((size_t)NTOK * C);
  float*    y   = allocF((size_t)NTOK * C);
  float*    q   = allocF((size_t)NTOK * C);
  float*    kb  = allocF((size_t)NTOK * C);
  float*    vb  = allocF((size_t)NTOK * C);
  unsigned* op  = allocU((size_t)NTOK * C);
  unsigned* Xgp = allocU((size_t)NKRP * C);
  unsigned* Hgp = allocU((size_t)NKRP * H4);
  float*    Yg  = allocF((size_t)NKRP * C);
  float*    tp  = allocF(NKR);
  int* ti     = (int*)w; w += NKR * 4;
  int* posA   = (int*)w; w += NKR * 4;
  int* rowOf  = (int*)w; w += NKR * 4;
  int* counts = (int*)w; w += NE * 4;
  int* offs   = (int*)w; w += NE * 4;

  k_embed<<<NTOK, 256, 0, stream>>>(idx, tok, pose, xp);

  for (int l = 0; l < NL; ++l) {
    k_qkv<<<dim3(C / 128, NTOK / 128, 3), 256, 0, stream>>>(
        xp, Wq + (size_t)l * C * C, Wk + (size_t)l * C * C, Wv + (size_t)l * C * C,
        q, kb, vb);
    k_attn<<<NB * HN, 256, 0, stream>>>(q, kb, vb, op);
    k_wo<<<dim3(C / 128, NTOK / 128), 256, 0, stream>>>(
        op, Wo + (size_t)l * C * C, bo + (size_t)l * C, y);
    k_ln<<<NTOK, 256, 0, stream>>>(xp, y, ln1g + (size_t)l * C, ln1b + (size_t)l * C, xp);

    hipMemsetAsync(counts, 0, NE * sizeof(int), stream);
    k_gate<<<NTOK, 64, 0, stream>>>(xp, gW + (size_t)l * C * NE, gb + (size_t)l * NE,
                                    ti, tp, posA, counts);
    k_offs<<<1, 64, 0, stream>>>(counts, offs);
    k_gather<<<NKR, 64, 0, stream>>>(xp, ti, posA, offs, rowOf, Xgp);
    k_w1<<<dim3(H4 / 128, NKR / 128, NE), 256, 0, stream>>>(
        Xgp, W1 + (size_t)l * NE * C * H4, b1 + (size_t)l * NE * H4, Hgp, counts, offs);
    k_w2<<<dim3(C / 128, NKR / 128, NE), 256, 0, stream>>>(
        Hgp, W2 + (size_t)l * NE * H4 * C, b2 + (size_t)l * NE * C, Yg, counts, offs);
    k_ln_moe<<<NTOK, 256, 0, stream>>>(xp, Yg, rowOf, tp,
                                       ln2g + (size_t)l * C, ln2b + (size_t)l * C, xp);
  }

  k_ln<<<NTOK, 256, 0, stream>>>(xp, nullptr, lnfg, lnfb, xp);
  k_head<<<dim3(1, NTOK / 128), 256, 0, stream>>>(xp, headW, headb, out);
}

// Round 4
// 4119.613 us; speedup vs baseline: 4.0752x; 3.0194x over previous
//
#include <hip/hip_runtime.h>
#include <math.h>

#define C    768
#define HN   8
#define HS   96
#define NE   8
#define NL   12
#define NV   95
#define TT   64
#define NB   16
#define NTOK 1024
#define H4   3072
#define NKR  2048
#define NKRP 2176
#define MC   (NTOK * C)

typedef __attribute__((ext_vector_type(8))) short short8;
typedef __attribute__((ext_vector_type(4))) float floatx4;

union U16x8 { uint4 u; short8 s; };
static __device__ __forceinline__ short8 as_s8(uint4 u) { U16x8 x; x.u = u; return x.s; }
static __device__ __forceinline__ uint4 ror16x4(uint4 q) {
  uint4 r;
  r.x = (q.x >> 16) | (q.x << 16);
  r.y = (q.y >> 16) | (q.y << 16);
  r.z = (q.z >> 16) | (q.z << 16);
  r.w = (q.w >> 16) | (q.w << 16);
  return r;
}

// packed split: low16 = bf16(hi), high16 = bf16(residual); hi+lo ~ f to 2^-17 rel
static __device__ __forceinline__ unsigned pack_split(float f) {
  unsigned u = __float_as_uint(f);
  unsigned h = (u + 0x7fffu + ((u >> 16) & 1u)) >> 16;
  float d = f - __uint_as_float(h << 16);
  unsigned v = __float_as_uint(d);
  unsigned l = (v + 0x7fffu + ((v >> 16) & 1u)) >> 16;
  return h | (l << 16);
}
static __device__ __forceinline__ float unpack_split(unsigned w) {
  return __uint_as_float(w << 16) + __uint_as_float(w & 0xffff0000u);
}

// ---------------- double-bf16 MFMA GEMM core --------------------------------
// A packed u32 [row][K] in registers (per-lane loads, round-2-proven path).
// W fp32 [K][N] -> LDS packed-split, col-major + XOR swizzle, double-buffered.
// Two MFMA passes ([h,l]-B and 16-bit-rotated B) give exactly (Ah+Al)(Bh+Bl).
// Block = 256 thr = 4 waves; each wave 32 rows x 128 cols; tile 128x128; BK=32.
// OUTMODE: 1 = bias+gelu+packed out, 2 = fp32 partial (no bias)
template<int OUTMODE>
static __device__ __forceinline__ void gemm_body(
    const unsigned* __restrict__ Ap, const int* __restrict__ perm,
    const float* __restrict__ W, const float* __restrict__ bias,
    float* __restrict__ outF, unsigned* __restrict__ outP,
    int row0, int Mend, int col0, int N, int K, int kbeg, int kend)
{
  __shared__ __align__(16) unsigned Bt[2][128 * 32];
  const int tid  = threadIdx.x;
  const int lane = tid & 63, wv = tid >> 6;
  const int l16  = lane & 15, lq = lane >> 4;
  const int sw   = (l16 & 7) << 2;   // B read-side XOR swizzle

  int ra0 = row0 + wv * 32 + l16;
  int ra1 = ra0 + 16;
  if (perm) { ra0 = perm[ra0]; ra1 = perm[ra1]; }
  const unsigned* A0 = Ap + (size_t)ra0 * K;
  const unsigned* A1 = Ap + (size_t)ra1 * K;

  // B staging: thread -> col (tid&127), k-quad-half (tid>>7)
  const int bcol = tid & 127;
  const int bqh  = (tid >> 7) * 4;
  int bcg = col0 + bcol; if (bcg >= N) bcg = N - 1;   // clamp; junk cols masked at store
  const float* Wb = W + bcg;
  const int bswz = (bcol & 7) << 2;
  float bw[16];
  auto loadB = [&](int kpos) {
    #pragma unroll
    for (int qq = 0; qq < 4; ++qq) {
      int kr = kpos + (bqh + qq) * 4;
      #pragma unroll
      for (int i = 0; i < 4; ++i) bw[qq * 4 + i] = Wb[(size_t)(kr + i) * N];
    }
  };
  auto writeB = [&](int buf) {
    #pragma unroll
    for (int qq = 0; qq < 4; ++qq) {
      uint4 u;
      u.x = pack_split(bw[qq * 4 + 0]); u.y = pack_split(bw[qq * 4 + 1]);
      u.z = pack_split(bw[qq * 4 + 2]); u.w = pack_split(bw[qq * 4 + 3]);
      *(uint4*)&Bt[buf][bcol * 32 + (((bqh + qq) * 4) ^ bswz)] = u;
    }
  };

  uint4 ac0[2], ac1[2];
  auto loadA = [&](int kpos, uint4* d0, uint4* d1) {
    const unsigned* p = A0 + kpos;
    d0[0] = *(const uint4*)(p + lq * 4);
    d0[1] = *(const uint4*)(p + 16 + lq * 4);
    p = A1 + kpos;
    d1[0] = *(const uint4*)(p + lq * 4);
    d1[1] = *(const uint4*)(p + 16 + lq * 4);
  };

  floatx4 acc[2][8];
  #pragma unroll
  for (int h = 0; h < 2; ++h)
    #pragma unroll
    for (int f = 0; f < 8; ++f) acc[h][f] = (floatx4){0, 0, 0, 0};

  const int ns = (kend - kbeg) >> 5;
  loadB(kbeg); loadA(kbeg, ac0, ac1); writeB(0);

  for (int s = 0; s < ns; ++s) {
    const int b = s & 1;
    __syncthreads();
    const int kn = kbeg + ((s + 1 < ns) ? (s + 1) * 32 : s * 32);
    loadB(kn);                         // issue next-step global loads early (T14)
    uint4 na0[2], na1[2];
    loadA(kn, na0, na1);
    const unsigned* bp = Bt[b];
    #pragma unroll
    for (int f = 0; f < 8; ++f) {
      const unsigned* base = bp + (f * 16 + l16) * 32;
      uint4 q0 = *(const uint4*)(base + ((4 * lq) ^ sw));
      uint4 q1 = *(const uint4*)(base + ((16 + 4 * lq) ^ sw));
      short8 b0 = as_s8(q0), b0r = as_s8(ror16x4(q0));
      short8 b1 = as_s8(q1), b1r = as_s8(ror16x4(q1));
      short8 a00 = as_s8(ac0[0]), a01 = as_s8(ac0[1]);
      short8 a10 = as_s8(ac1[0]), a11 = as_s8(ac1[1]);
      acc[0][f] = __builtin_amdgcn_mfma_f32_16x16x32_bf16(a00, b0,  acc[0][f], 0, 0, 0);
      acc[1][f] = __builtin_amdgcn_mfma_f32_16x16x32_bf16(a10, b0,  acc[1][f], 0, 0, 0);
      acc[0][f] = __builtin_amdgcn_mfma_f32_16x16x32_bf16(a00, b0r, acc[0][f], 0, 0, 0);
      acc[1][f] = __builtin_amdgcn_mfma_f32_16x16x32_bf16(a10, b0r, acc[1][f], 0, 0, 0);
      acc[0][f] = __builtin_amdgcn_mfma_f32_16x16x32_bf16(a01, b1,  acc[0][f], 0, 0, 0);
      acc[1][f] = __builtin_amdgcn_mfma_f32_16x16x32_bf16(a11, b1,  acc[1][f], 0, 0, 0);
      acc[0][f] = __builtin_amdgcn_mfma_f32_16x16x32_bf16(a01, b1r, acc[0][f], 0, 0, 0);
      acc[1][f] = __builtin_amdgcn_mfma_f32_16x16x32_bf16(a11, b1r, acc[1][f], 0, 0, 0);
    }
    if (s + 1 < ns) writeB(b ^ 1);     // cvt + ds_write after compute
    ac0[0] = na0[0]; ac0[1] = na0[1]; ac1[0] = na1[0]; ac1[1] = na1[1];
  }

  const int rb = row0 + wv * 32 + lq * 4;
  #pragma unroll
  for (int h = 0; h < 2; ++h) {
    #pragma unroll
    for (int f = 0; f < 8; ++f) {
      int cc = col0 + f * 16 + l16;
      if (cc < N) {
        float bb = (OUTMODE == 1) ? bias[cc] : 0.f;
        #pragma unroll
        for (int r = 0; r < 4; ++r) {
          int rr = rb + h * 16 + r;
          if (rr < Mend) {
            float v = acc[h][f][r] + bb;
            if (OUTMODE == 1) {
              v = 0.5f * v * (1.f + erff(v * 0.70710678118654752f));
              outP[(size_t)rr * N + cc] = pack_split(v);
            } else {
              outF[(size_t)rr * N + cc] = v;
            }
          }
        }
      }
    }
  }
}

static __device__ __forceinline__ void expert_range(const int* counts, int e,
                                                    int& off, int& cnt) {
  off = 0; cnt = 0;
  #pragma unroll
  for (int i = 0; i < NE; ++i) {
    int c = counts[i];
    if (i < e) off += c;
    if (i == e) cnt = c;
  }
}

// ---------------- GEMM kernels ---------------------------------------------
__global__ void __launch_bounds__(256) k_qkv(const unsigned* xp, const float* Wq,
    const float* Wk, const float* Wv, float* qkvp) {
  int z = blockIdx.z, mat = z >> 1, ch = z & 1;
  const float* W = mat == 0 ? Wq : (mat == 1 ? Wk : Wv);
  gemm_body<2>(xp, nullptr, W, nullptr, qkvp + (size_t)z * MC, nullptr,
               blockIdx.y * 128, NTOK, blockIdx.x * 128, C, C, ch * 384, (ch + 1) * 384);
}

__global__ void __launch_bounds__(256) k_wo(const unsigned* op, const float* W,
    float* wop) {
  int ch = blockIdx.z;
  gemm_body<2>(op, nullptr, W, nullptr, wop + (size_t)ch * MC, nullptr,
               blockIdx.y * 128, NTOK, blockIdx.x * 128, C, C, ch * 128, (ch + 1) * 128);
}

__global__ void __launch_bounds__(256) k_w1(const unsigned* xp, const int* perm,
    const float* W1, const float* b1, unsigned* Hgp, const int* counts) {
  int e = blockIdx.z, off, cnt;
  expert_range(counts, e, off, cnt);
  int r0 = blockIdx.y * 128;
  if (r0 >= cnt) return;
  gemm_body<1>(xp, perm, W1 + (size_t)e * C * H4, b1 + (size_t)e * H4, nullptr, Hgp,
               off + r0, off + cnt, blockIdx.x * 128, H4, C, 0, C);
}

__global__ void __launch_bounds__(256) k_w2(const unsigned* Hgp, const float* W2,
    float* Ypart, const int* counts) {
  int z = blockIdx.z, e = z >> 2, ch = z & 3;
  int off, cnt;
  expert_range(counts, e, off, cnt);
  int r0 = blockIdx.y * 128;
  if (r0 >= cnt) return;
  gemm_body<2>(Hgp, nullptr, W2 + (size_t)e * H4 * C, nullptr,
               Ypart + (size_t)ch * NKRP * C, nullptr,
               off + r0, off + cnt, blockIdx.x * 128, C, H4, ch * 768, (ch + 1) * 768);
}

__global__ void __launch_bounds__(256) k_head(const unsigned* xp, const float* W,
    float* hpart) {
  int ch = blockIdx.z;
  gemm_body<2>(xp, nullptr, W, nullptr, hpart + (size_t)ch * NTOK * NV, nullptr,
               blockIdx.y * 128, NTOK, 0, NV, C, ch * 64, (ch + 1) * 64);
}

__global__ void k_headsum(const float* hpart, const float* headb, float* out) {
  int n = blockIdx.x, c = threadIdx.x;
  if (c < NV) {
    size_t i = (size_t)n * NV + c;
    float s = headb[c];
    #pragma unroll
    for (int ch = 0; ch < 12; ++ch) s += hpart[i + (size_t)ch * NTOK * NV];
    out[i] = s;
  }
}

// ---------------- small ops ------------------------------------------------
__global__ void k_embed(const int* __restrict__ idx, const float* __restrict__ tok,
                        const float* __restrict__ pos, unsigned* __restrict__ xp) {
  int n = blockIdx.x; int t = n & (TT - 1);
  int token = idx[n];
  for (int j = threadIdx.x; j < C; j += 256)
    xp[(size_t)n * C + j] = pack_split(tok[(size_t)token * C + j] + pos[(size_t)t * C + j]);
}

static __device__ __forceinline__ void ln_finish(int tid, float* v, const float* g,
                                                 const float* bb, unsigned* outrow,
                                                 float* sp) {
  int lane = tid & 63, wid = tid >> 6;
  float s = v[0] + v[1] + v[2];
  for (int o = 32; o; o >>= 1) s += __shfl_down(s, o);
  if (!lane) sp[wid] = s;
  __syncthreads();
  float mean = (sp[0] + sp[1] + sp[2] + sp[3]) * (1.f / C);
  __syncthreads();
  float d0 = v[0] - mean, d1 = v[1] - mean, d2 = v[2] - mean;
  float qq = d0 * d0 + d1 * d1 + d2 * d2;
  for (int o = 32; o; o >>= 1) qq += __shfl_down(qq, o);
  if (!lane) sp[wid] = qq;
  __syncthreads();
  float var = (sp[0] + sp[1] + sp[2] + sp[3]) * (1.f / C);
  float rs = rsqrtf(var + 1e-5f);
  #pragma unroll
  for (int i = 0; i < 3; ++i) {
    int c = tid + i * 256;
    v[i] = (v[i] - mean) * rs * g[c] + bb[c];
    outrow[c] = pack_split(v[i]);
  }
}

// ln1 + gate fused
__global__ void __launch_bounds__(256) k_ln1g(unsigned* __restrict__ xp,
    const float* __restrict__ wop, const float* __restrict__ bo,
    const float* __restrict__ g, const float* __restrict__ bb,
    const float* __restrict__ gW, const float* __restrict__ gb,
    int* __restrict__ ti, float* __restrict__ tp, int* __restrict__ pos,
    int* __restrict__ counts) {
  int n = blockIdx.x; int tid = threadIdx.x;
  __shared__ float sp[4];
  __shared__ float gs[4][NE];
  float v[3];
  #pragma unroll
  for (int i = 0; i < 3; ++i) {
    int c = tid + i * 256;
    size_t gi = (size_t)n * C + c;
    float acc = unpack_split(xp[gi]) + bo[c];
    #pragma unroll
    for (int ch = 0; ch < 6; ++ch) acc += wop[gi + (size_t)ch * MC];
    v[i] = acc;
  }
  ln_finish(tid, v, g, bb, xp + (size_t)n * C, sp);
  float a[NE];
  #pragma unroll
  for (int e = 0; e < NE; ++e) a[e] = 0.f;
  #pragma unroll
  for (int i = 0; i < 3; ++i) {
    int c = tid + i * 256;
    const float* gr = gW + (size_t)c * NE;
    #pragma unroll
    for (int e = 0; e < NE; ++e) a[e] += v[i] * gr[e];
  }
  int lane = tid & 63, wid = tid >> 6;
  #pragma unroll
  for (int e = 0; e < NE; ++e)
    for (int o = 32; o; o >>= 1) a[e] += __shfl_down(a[e], o);
  if (!lane)
    #pragma unroll
    for (int e = 0; e < NE; ++e) gs[wid][e] = a[e];
  __syncthreads();
  if (tid == 0) {
    float p[NE]; float m = -1e30f;
    #pragma unroll
    for (int e = 0; e < NE; ++e) {
      p[e] = gs[0][e] + gs[1][e] + gs[2][e] + gs[3][e] + gb[e];
      m = fmaxf(m, p[e]);
    }
    float den = 0.f;
    #pragma unroll
    for (int e = 0; e < NE; ++e) { p[e] = expf(p[e] - m); den += p[e]; }
    float inv = 1.f / den;
    #pragma unroll
    for (int e = 0; e < NE; ++e) p[e] *= inv;
    int e0 = 0;
    for (int e = 1; e < NE; ++e) if (p[e] > p[e0]) e0 = e;
    int e1 = -1;
    for (int e = 0; e < NE; ++e) if (e != e0 && (e1 < 0 || p[e] > p[e1])) e1 = e;
    float ss = p[e0] + p[e1];
    int p0 = atomicAdd(&counts[e0], 1), p1 = atomicAdd(&counts[e1], 1);
    ti[n * 2] = e0;  ti[n * 2 + 1] = e1;
    pos[n * 2] = p0; pos[n * 2 + 1] = p1;
    tp[n * 2] = p[e0] / ss; tp[n * 2 + 1] = p[e1] / ss;
  }
}

__global__ void k_perm(const int* __restrict__ ti, const int* __restrict__ pos,
                       const int* __restrict__ counts, int* __restrict__ rowOf,
                       int* __restrict__ perm) {
  int a = blockIdx.x * 256 + threadIdx.x;
  if (a >= NKRP) return;
  if (a >= NKR) { perm[a] = 0; return; }
  int e = ti[a];
  int off = 0;
  #pragma unroll
  for (int i = 0; i < NE; ++i) if (i < e) off += counts[i];
  int row = off + pos[a];
  rowOf[a] = row;
  perm[row] = a >> 1;
}

// moe combine + ln2 fused
__global__ void __launch_bounds__(256) k_ln_moe(unsigned* __restrict__ xp,
    const float* __restrict__ Ypart, const int* __restrict__ rowOf,
    const int* __restrict__ ti, const float* __restrict__ tp,
    const float* __restrict__ b2, const float* __restrict__ g,
    const float* __restrict__ bb) {
  int n = blockIdx.x; int tid = threadIdx.x;
  __shared__ float sp[4];
  int r0 = rowOf[n * 2], r1 = rowOf[n * 2 + 1];
  int e0 = ti[n * 2], e1 = ti[n * 2 + 1];
  float w0 = tp[n * 2], w1 = tp[n * 2 + 1];
  const float* bz0 = b2 + (size_t)e0 * C;
  const float* bz1 = b2 + (size_t)e1 * C;
  float v[3];
  #pragma unroll
  for (int i = 0; i < 3; ++i) {
    int c = tid + i * 256;
    float y0 = bz0[c], y1 = bz1[c];
    #pragma unroll
    for (int ch = 0; ch < 4; ++ch) {
      const float* pl = Ypart + (size_t)ch * NKRP * C;
      y0 += pl[(size_t)r0 * C + c];
      y1 += pl[(size_t)r1 * C + c];
    }
    v[i] = unpack_split(xp[(size_t)n * C + c]) + w0 * y0 + w1 * y1;
  }
  ln_finish(tid, v, g, bb, xp + (size_t)n * C, sp);
}

__global__ void __launch_bounds__(256) k_lnf(unsigned* __restrict__ xp,
    const float* __restrict__ g, const float* __restrict__ bb) {
  int n = blockIdx.x; int tid = threadIdx.x;
  __shared__ float sp[4];
  float v[3];
  #pragma unroll
  for (int i = 0; i < 3; ++i) v[i] = unpack_split(xp[(size_t)n * C + tid + i * 256]);
  ln_finish(tid, v, g, bb, xp + (size_t)n * C, sp);
}

// attention: 48KB LDS (qs reused for probs, kv reused K->V), register scores,
// wave-parallel softmax over 4-lane groups
__global__ void __launch_bounds__(256) k_attn(const float* __restrict__ qkvp,
    unsigned* __restrict__ op, int* __restrict__ counts) {
  int bh = blockIdx.x; int b = bh >> 3, h = bh & 7;
  int tid = threadIdx.x;
  if (bh == 0 && tid < NE) counts[tid] = 0;
  __shared__ float qs[TT][HS];
  __shared__ float kv[TT][HS];
  const float* q0 = qkvp;                  const float* q1 = qkvp + MC;
  const float* k0 = qkvp + 2 * (size_t)MC; const float* k1 = qkvp + 3 * (size_t)MC;
  const float* v0 = qkvp + 4 * (size_t)MC; const float* v1 = qkvp + 5 * (size_t)MC;
  for (int i = tid; i < TT * HS; i += 256) {
    int t = i / HS, d = i % HS;
    size_t gi = (size_t)(b * TT + t) * C + h * HS + d;
    qs[t][d] = q0[gi] + q1[gi];
    kv[t][d] = k0[gi] + k1[gi];
  }
  __syncthreads();
  int r = tid >> 2, g = tid & 3;
  const float scale = 0.10206207261596575f;   // 96^-0.5
  float sreg[16];
  {
    const floatx4* q4 = (const floatx4*)&qs[r][0];
    #pragma unroll
    for (int j = 0; j < 16; ++j) {
      int kk = g * 16 + j;
      float s = -1e30f;
      if (kk <= r) {
        const floatx4* k4 = (const floatx4*)&kv[kk][0];
        float a2 = 0.f;
        #pragma unroll
        for (int d4 = 0; d4 < HS / 4; ++d4) {
          floatx4 a = q4[d4], bbv = k4[d4];
          a2 += a[0]*bbv[0] + a[1]*bbv[1] + a[2]*bbv[2] + a[3]*bbv[3];
        }
        s = a2 * scale;
      }
      sreg[j] = s;
    }
  }
  // 4-lane-group softmax (lanes r*4+g, g=0..3, same wave)
  float m = sreg[0];
  #pragma unroll
  for (int j = 1; j < 16; ++j) m = fmaxf(m, sreg[j]);
  m = fmaxf(m, __shfl_xor(m, 1));
  m = fmaxf(m, __shfl_xor(m, 2));
  float den = 0.f;
  #pragma unroll
  for (int j = 0; j < 16; ++j) { sreg[j] = expf(sreg[j] - m); den += sreg[j]; }
  den += __shfl_xor(den, 1);
  den += __shfl_xor(den, 2);
  float inv = 1.f / den;
  __syncthreads();               // all qs/kv reads done
  float (*psc)[TT] = (float(*)[TT])&qs[0][0];   // reuse qs for probs
  #pragma unroll
  for (int j = 0; j < 16; ++j) psc[r][g * 16 + j] = sreg[j] * inv;
  for (int i = tid; i < TT * HS; i += 256) {    // reuse kv for V
    int t = i / HS, d = i % HS;
    size_t gi = (size_t)(b * TT + t) * C + h * HS + d;
    kv[t][d] = v0[gi] + v1[gi];
  }
  __syncthreads();
  floatx4 accv[6];
  #pragma unroll
  for (int cc = 0; cc < 6; ++cc) accv[cc] = (floatx4){0, 0, 0, 0};
  for (int kk = 0; kk < TT; ++kk) {
    float wgt = psc[r][kk];
    const floatx4* v4 = (const floatx4*)&kv[kk][0];
    #pragma unroll
    for (int cc = 0; cc < 6; ++cc) accv[cc] += wgt * v4[g * 6 + cc];
  }
  unsigned* orow = op + (size_t)(b * TT + r) * C + h * HS + g * 24;
  #pragma unroll
  for (int cc = 0; cc < 6; ++cc)
    #pragma unroll
    for (int mm = 0; mm < 4; ++mm) orow[cc * 4 + mm] = pack_split(accv[cc][mm]);
}

// ---------------- driver ---------------------------------------------------
extern "C" void kernel_launch(void* const* d_in, const int* in_sizes, int n_in,
                              void* d_out, int out_size, void* d_ws, size_t ws_size,
                              hipStream_t stream) {
  const int*   idx   = (const int*)d_in[0];
  const float* tok   = (const float*)d_in[1];
  const float* pose  = (const float*)d_in[2];
  const float* Wq    = (const float*)d_in[3];
  const float* Wk    = (const float*)d_in[4];
  const float* Wv    = (const float*)d_in[5];
  const float* Wo    = (const float*)d_in[6];
  const float* bo    = (const float*)d_in[7];
  const float* gW    = (const float*)d_in[8];
  const float* gb    = (const float*)d_in[9];
  const float* W1    = (const float*)d_in[10];
  const float* b1    = (const float*)d_in[11];
  const float* W2    = (const float*)d_in[12];
  const float* b2    = (const float*)d_in[13];
  const float* ln1g  = (const float*)d_in[14];
  const float* ln1b  = (const float*)d_in[15];
  const float* ln2g  = (const float*)d_in[16];
  const float* ln2b  = (const float*)d_in[17];
  const float* lnfg  = (const float*)d_in[18];
  const float* lnfb  = (const float*)d_in[19];
  const float* headW = (const float*)d_in[20];
  const float* headb = (const float*)d_in[21];
  float* out = (float*)d_out;

  if (ws_size < (size_t)160 * 1024 * 1024) return;
  char* w = (char*)d_ws;
  auto allocU = [&](size_t n) { unsigned* p = (unsigned*)w; w += n * 4; return p; };
  auto allocF = [&](size_t n) { float* p = (float*)w; w += n * 4; return p; };
  unsigned* xp    = allocU((size_t)MC);
  unsigned* op    = allocU((size_t)MC);
  float*    qkvp  = allocF((size_t)6 * MC);
  float*    wop   = allocF((size_t)6 * MC);
  unsigned* Hgp   = allocU((size_t)NKRP * H4);
  float*    Ypart = allocF((size_t)4 * NKRP * C);
  float*    hpart = allocF((size_t)12 * NTOK * NV);
  float*    tp    = allocF(NKR);
  int* ti     = (int*)w; w += NKR * 4;
  int* posA   = (int*)w; w += NKR * 4;
  int* rowOf  = (int*)w; w += NKR * 4;
  int* perm   = (int*)w; w += NKRP * 4;
  int* counts = (int*)w; w += NE * 4;

  k_embed<<<NTOK, 256, 0, stream>>>(idx, tok, pose, xp);

  for (int l = 0; l < NL; ++l) {
    k_qkv<<<dim3(6, 8, 6), 256, 0, stream>>>(
        xp, Wq + (size_t)l * C * C, Wk + (size_t)l * C * C, Wv + (size_t)l * C * C, qkvp);
    k_attn<<<NB * HN, 256, 0, stream>>>(qkvp, op, counts);
    k_wo<<<dim3(6, 8, 6), 256, 0, stream>>>(op, Wo + (size_t)l * C * C, wop);
    k_ln1g<<<NTOK, 256, 0, stream>>>(xp, wop, bo + (size_t)l * C,
        ln1g + (size_t)l * C, ln1b + (size_t)l * C,
        gW + (size_t)l * C * NE, gb + (size_t)l * NE, ti, tp, posA, counts);
    k_perm<<<(NKRP + 255) / 256, 256, 0, stream>>>(ti, posA, counts, rowOf, perm);
    k_w1<<<dim3(24, 8, 8), 256, 0, stream>>>(xp, perm,
        W1 + (size_t)l * NE * C * H4, b1 + (size_t)l * NE * H4, Hgp, counts);
    k_w2<<<dim3(6, 8, 32), 256, 0, stream>>>(Hgp,
        W2 + (size_t)l * NE * H4 * C, Ypart, counts);
    k_ln_moe<<<NTOK, 256, 0, stream>>>(xp, Ypart, rowOf, ti, tp,
        b2 + (size_t)l * NE * C, ln2g + (size_t)l * C, ln2b + (size_t)l * C);
  }

  k_lnf<<<NTOK, 256, 0, stream>>>(xp, lnfg, lnfb);
  k_head<<<dim3(1, 8, 12), 256, 0, stream>>>(xp, headW, hpart);
  k_headsum<<<NTOK, 128, 0, stream>>>(hpart, headb, out);
}